// Round 10
// baseline (565.124 us; speedup 1.0000x reference)
//
#include <hip/hip_runtime.h>
#include <stdint.h>

#define NROWS   32768
#define NCODES  8192
#define DIM     256
#define NSPLIT  8
#define CPS     1024
#define MAXFIX  24576
#define MAXPAIRS 262144
#define MAXRESC (MAXFIX * NSPLIT)

typedef __attribute__((ext_vector_type(8))) _Float16 f16x8;
typedef __attribute__((ext_vector_type(4))) float f32x4;

// convert 8 fp32 (16B-aligned) to fp16 RNE
__device__ __forceinline__ f16x8 cvt8h(const float* __restrict__ p) {
    float4 a = *(const float4*)p;
    float4 b = *(const float4*)(p + 4);
    f16x8 H;
    H[0] = (_Float16)a.x; H[1] = (_Float16)a.y;
    H[2] = (_Float16)a.z; H[3] = (_Float16)a.w;
    H[4] = (_Float16)b.x; H[5] = (_Float16)b.y;
    H[6] = (_Float16)b.z; H[7] = (_Float16)b.w;
    return H;
}

// ------- K_prep: [blocks 0..1023] cb -> fp16(c*8192) XOR-permuted + max||c||^2
//                 [blocks 1024..2047] bit-exact pairwise fp32 sum of z*z per row -------
__global__ __launch_bounds__(256) void k_prep(const float* __restrict__ cb,
                                              const float* __restrict__ z,
                                              unsigned short* __restrict__ bh,
                                              unsigned* __restrict__ cmax2,
                                              float* __restrict__ sum1) {
    __shared__ float zz[32 * 257];
    const int t = threadIdx.x;
    if (blockIdx.x < 1024) {
        int i = blockIdx.x * 256 + t;               // global 16B-unit index
        const float* p = cb + (size_t)i * 8;
        float4 a = *(const float4*)p;
        float4 b = *(const float4*)(p + 4);
        f16x8 H;
        H[0] = (_Float16)(a.x * 8192.0f); H[1] = (_Float16)(a.y * 8192.0f);
        H[2] = (_Float16)(a.z * 8192.0f); H[3] = (_Float16)(a.w * 8192.0f);
        H[4] = (_Float16)(b.x * 8192.0f); H[5] = (_Float16)(b.y * 8192.0f);
        H[6] = (_Float16)(b.z * 8192.0f); H[7] = (_Float16)(b.w * 8192.0f);
        int j = (i & ~31) | ((i & 31) ^ ((i >> 5) & 7));
        *(f16x8*)(bh + (size_t)j * 8) = H;
        float ss = a.x*a.x + a.y*a.y + a.z*a.z + a.w*a.w
                 + b.x*b.x + b.y*b.y + b.z*b.z + b.w*b.w;
        #pragma unroll
        for (int off = 1; off < 32; off <<= 1) ss += __shfl_xor(ss, off);
        if ((t & 31) == 0) atomicMax(cmax2, __float_as_uint(ss));
        return;
    }
    const int bid = blockIdx.x - 1024;
    const size_t base = (size_t)bid * 32 * 256;
    #pragma unroll
    for (int k = 0; k < 8; ++k) {
        int f4 = t + k * 256;                       // 0..2047
        float4 v = *(const float4*)(z + base + (size_t)f4 * 4);
        int row = f4 >> 6, col = (f4 & 63) * 4;
        float* d = &zz[row * 257 + col];
        d[0] = v.x * v.x; d[1] = v.y * v.y; d[2] = v.z * v.z; d[3] = v.w * v.w;
    }
    __syncthreads();
    if (t < 32) {
        const float* x = &zz[t * 257];
        float tot = 0.0f;
        #pragma unroll
        for (int h = 0; h < 2; ++h) {
            float r0 = x[0], r1 = x[1], r2 = x[2], r3 = x[3];
            float r4 = x[4], r5 = x[5], r6 = x[6], r7 = x[7];
            for (int i = 8; i < 128; i += 8) {
                r0 += x[i + 0]; r1 += x[i + 1]; r2 += x[i + 2]; r3 += x[i + 3];
                r4 += x[i + 4]; r5 += x[i + 5]; r6 += x[i + 6]; r7 += x[i + 7];
            }
            float bsum = ((r0 + r1) + (r2 + r3)) + ((r4 + r5) + (r6 + r7));
            tot = (h == 0) ? bsum : (tot + bsum);
            x += 128;
        }
        sum1[bid * 32 + t] = tot;
    }
}

// async-stage one 32-code fp16 half-tile (16 KiB) into linear LDS via global->LDS DMA.
__device__ __forceinline__ void stage_h(const unsigned short* __restrict__ gh,
                                        int cbase, int w, int lane,
                                        unsigned short* B) {
    const unsigned short* sh = gh + (size_t)cbase * 256;
    #pragma unroll
    for (int k = 0; k < 4; ++k) {
        const int ub = k * 256 + w * 64;            // 16B-unit base for this wave/call
        __builtin_amdgcn_global_load_lds(
            (const __attribute__((address_space(1))) void*)(sh + (size_t)(ub + lane) * 8),
            (__attribute__((address_space(3))) void*)(B + (size_t)ub * 8), 16, 0, 0);
    }
}

// ------- K1: fp16 MAX-dot GEMM, indexless med3 top-3 with index-in-mantissa keys -------
// 64-code rounds (32 KiB tile, double-buffered): halves the round count so the per-round
// fixed cost (stage-issue + barrier drain + ds_read warm-up) is amortized over 2x MFMA.
// Same verified structure as the 183us round-8 kernel: one __syncthreads per round whose
// implicit vmcnt(0) drains the NEXT round's loads (issued a full round earlier).
// (Round-7 lesson: launch_bounds(256,4) spills A-frags -> keep (256,2), 128 VGPR.)
__global__ __launch_bounds__(256, 2) void k_dist(
    const float* __restrict__ z,
    const unsigned short* __restrict__ bh,
    float* __restrict__ pm1, float* __restrict__ pm2, float* __restrict__ pm3)
{
    __shared__ __align__(16) unsigned short Bs[2][64][256];      // 2 x 32 KiB buffers

    const int bid   = blockIdx.x;                   // 128 row-tiles x 8 splits
    const int split = bid & (NSPLIT - 1);
    const int rt    = bid >> 3;
    const int rowbase = rt * 256;
    const int cbase0  = split * CPS;

    const int t    = threadIdx.x;
    const int w    = t >> 6;
    const int lane = t & 63;
    const int quad = lane >> 4;
    const int l15  = lane & 15;

    // prologue: kick round-0 DMA (64 codes = 2 half-tiles), convert A under its latency
    stage_h(bh, cbase0,      w, lane, &Bs[0][0][0]);
    stage_h(bh, cbase0 + 32, w, lane, &Bs[0][32][0]);

    f16x8 Af[4][8];                                  // 64 rows x K=256 fp16
    const int rbase = rowbase + w * 64;
    #pragma unroll
    for (int mt = 0; mt < 4; ++mt) {
        const float* zp = z + (size_t)(rbase + mt*16 + l15) * DIM + quad * 8;
        #pragma unroll
        for (int ks = 0; ks < 8; ++ks)
            Af[mt][ks] = cvt8h(zp + ks * 32);
    }

    // swizzled LDS byte offsets; code cc = nt*16+l15 -> +nt*8192 imm ((nt*16+l15)&7 == l15&7)
    int offB[8];
    const int cx = l15 & 7;
    #pragma unroll
    for (int ks = 0; ks < 8; ++ks)
        offB[ks] = l15 * 512 + (((quad + 4 * ks) ^ cx) * 16);
    const unsigned idx0 = 8191u - (unsigned)(cbase0 + l15);      // nt=0 index bits @round 0

    float m1[16], m2[16], m3[16];
    #pragma unroll
    for (int s = 0; s < 16; ++s) { m1[s] = -3.4e38f; m2[s] = -3.4e38f; m3[s] = -3.4e38f; }

    __syncthreads();                                 // round-0 tile ready (vmcnt drained)

#define KD_ROUND(RND, BCUR, BNXT)                                               \
    {                                                                           \
        if ((RND) + 1 < CPS / 64) {                                             \
            stage_h(bh, cbase0 + ((RND) + 1) * 64,      w, lane, (BNXT));       \
            stage_h(bh, cbase0 + ((RND) + 1) * 64 + 32, w, lane, (BNXT) + 32 * 256); \
        }                                                                       \
        const char* baseB = (const char*)(BCUR);                                \
        _Pragma("unroll")                                                       \
        for (int nt = 0; nt < 4; ++nt) {                                        \
            f32x4 a0 = {0,0,0,0}, a1 = {0,0,0,0}, a2 = {0,0,0,0}, a3 = {0,0,0,0};\
            _Pragma("unroll")                                                   \
            for (int ks = 0; ks < 8; ++ks) {                                    \
                f16x8 Bk = *(const f16x8*)(baseB + offB[ks] + nt * 8192);       \
                a0 = __builtin_amdgcn_mfma_f32_16x16x32_f16(Af[0][ks], Bk, a0, 0, 0, 0); \
                a1 = __builtin_amdgcn_mfma_f32_16x16x32_f16(Af[1][ks], Bk, a1, 0, 0, 0); \
                a2 = __builtin_amdgcn_mfma_f32_16x16x32_f16(Af[2][ks], Bk, a2, 0, 0, 0); \
                a3 = __builtin_amdgcn_mfma_f32_16x16x32_f16(Af[3][ks], Bk, a3, 0, 0, 0); \
            }                                                                   \
            const unsigned ibnt = idx0 - (unsigned)((RND) * 64 + nt * 16);      \
            _Pragma("unroll")                                                   \
            for (int mt = 0; mt < 4; ++mt) {                                    \
                _Pragma("unroll")                                               \
                for (int r = 0; r < 4; ++r) {                                   \
                    float dot = mt == 0 ? a0[r] : mt == 1 ? a1[r] : mt == 2 ? a2[r] : a3[r]; \
                    unsigned kb = (__float_as_uint(dot) & 0xFFFFE000u) | ibnt;  \
                    float kf = __uint_as_float(kb);                             \
                    int s = mt * 4 + r;                                         \
                    m3[s] = __builtin_amdgcn_fmed3f(m2[s], m3[s], kf);          \
                    m2[s] = __builtin_amdgcn_fmed3f(m1[s], m2[s], kf);          \
                    m1[s] = fmaxf(m1[s], kf);                                   \
                }                                                               \
            }                                                                   \
        }                                                                       \
        __syncthreads();                                                        \
    }

    for (int r2 = 0; r2 < CPS / 128; ++r2) {
        KD_ROUND(2 * r2,     &Bs[0][0][0], &Bs[1][0][0]);
        KD_ROUND(2 * r2 + 1, &Bs[1][0][0], &Bs[0][0][0]);
    }
#undef KD_ROUND

    #pragma unroll
    for (int off = 1; off < 16; off <<= 1) {
        #pragma unroll
        for (int s = 0; s < 16; ++s) {
            float o1 = __shfl_xor(m1[s], off);
            float o2 = __shfl_xor(m2[s], off);
            float o3 = __shfl_xor(m3[s], off);
            m3[s] = __builtin_amdgcn_fmed3f(m2[s], m3[s], o1);
            m2[s] = __builtin_amdgcn_fmed3f(m1[s], m2[s], o1);
            m1[s] = fmaxf(m1[s], o1);
            m3[s] = __builtin_amdgcn_fmed3f(m2[s], m3[s], o2);
            m2[s] = __builtin_amdgcn_fmed3f(m1[s], m2[s], o2);
            m1[s] = fmaxf(m1[s], o2);
            m3[s] = __builtin_amdgcn_fmed3f(m2[s], m3[s], o3);
            m2[s] = __builtin_amdgcn_fmed3f(m1[s], m2[s], o3);
            m1[s] = fmaxf(m1[s], o3);
        }
    }
    if (l15 == 0) {
        #pragma unroll
        for (int s = 0; s < 16; ++s) {
            int mt = s >> 2, r = s & 3;
            int row = rbase + mt * 16 + quad * 4 + r;
            pm1[row * NSPLIT + split] = m1[s];
            pm2[row * NSPLIT + split] = m2[s];
            pm3[row * NSPLIT + split] = m3[s];
        }
    }
}

// ------- K2: merge splits; flag ambiguous rows (emit split-top-3 candidates, rescan
//         requests); count histogram for unflagged rows. -------
__global__ void k_combine(const float* __restrict__ pm1, const float* __restrict__ pm2,
                          const float* __restrict__ pm3, const float* __restrict__ sum1,
                          const unsigned* __restrict__ cmax2,
                          int* __restrict__ idx_i, float* __restrict__ out_idx,
                          int* __restrict__ flagc, int* __restrict__ fixl,
                          float* __restrict__ fixthr, int* __restrict__ npairs,
                          int2* __restrict__ pairs, int* __restrict__ nresc,
                          int2* __restrict__ resc, int* __restrict__ count)
{
    int r = blockIdx.x * 256 + threadIdx.x;
    float a[8], b[8], c[8];
    #pragma unroll
    for (int s = 0; s < NSPLIT; ++s) {
        a[s] = pm1[r * NSPLIT + s];
        b[s] = pm2[r * NSPLIT + s];
        c[s] = pm3[r * NSPLIT + s];
    }
    float M1 = -3.4e38f, M2 = -3.4e38f;
    #pragma unroll
    for (int s = 0; s < NSPLIT; ++s) {
        M2 = fmaxf(fmaxf(M2, b[s]), fminf(M1, a[s]));
        M1 = fmaxf(M1, a[s]);
    }
    int I1 = (int)(8191u - (__float_as_uint(M1) & 8191u));
    idx_i[r] = I1;
    out_idx[r] = (float)I1;
    float cn = sqrtf(__uint_as_float(*cmax2)) * 8192.0f;         // scaled max ||c||
    float ds = 9.80e-4f * sqrtf(sum1[r]) * cn + 3e-3f;           // scaled fp16-dot bound
    float t1 = sum1[r] - M1 * 0x1p-12f;                          // ref's fp32 dist value
    unsigned eb = (__float_as_uint(t1 + 0.05f) >> 23) & 0xFFu;   // biased exponent
    float q = __uint_as_float((eb - 23u) << 23);                 // ulp of t1's binade
    bool fixed = false;
    if (M1 - M2 <= (q + 2e-6f) * 8192.0f + 2.0f * ds + 0.0655f) {
        int p = atomicAdd(flagc, 1);
        if (p < MAXFIX) {
            fixed = true;
            fixl[p] = r;
            float thr = M1 - ((1.25f * q + 4e-6f) * 8192.0f + 2.2f * ds + 0.16f);
            fixthr[p] = thr;
            #pragma unroll
            for (int s = 0; s < NSPLIT; ++s) {
                if (a[s] >= thr) {
                    int pp = atomicAdd(npairs, 1);
                    if (pp < MAXPAIRS)
                        pairs[pp] = make_int2(p, (int)(8191u - (__float_as_uint(a[s]) & 8191u)));
                }
                if (b[s] >= thr) {
                    int pp = atomicAdd(npairs, 1);
                    if (pp < MAXPAIRS)
                        pairs[pp] = make_int2(p, (int)(8191u - (__float_as_uint(b[s]) & 8191u)));
                }
                if (c[s] >= thr) {                   // codes ranked >=3 unbounded: rescan split
                    int pp = atomicAdd(npairs, 1);
                    if (pp < MAXPAIRS)
                        pairs[pp] = make_int2(p, (int)(8191u - (__float_as_uint(c[s]) & 8191u)));
                    int q2 = atomicAdd(nresc, 1);
                    if (q2 < MAXRESC) resc[q2] = make_int2(p, s);
                }
            }
        }
    }
    if (!fixed) atomicAdd(&count[I1], 1);            // flagged rows counted in k_fin
}

// ------- K3: rare split rescans — fp32 dots, 4 codes in flight (latency-pipelined) -------
__global__ __launch_bounds__(256) void k_resc(
    const float* __restrict__ z, const float* __restrict__ cb,
    const int* __restrict__ nresc_p, const int2* __restrict__ resc,
    const int* __restrict__ fixl, const float* __restrict__ fixthr,
    int* __restrict__ npairs, int2* __restrict__ pairs)
{
    int nr = *nresc_p; if (nr > MAXRESC) nr = MAXRESC;
    const int w = threadIdx.x >> 6, lane = threadIdx.x & 63;
    for (int it = blockIdx.x; it < nr; it += gridDim.x) {
        const int slot = resc[it].x, split = resc[it].y;
        const int row = fixl[slot];
        const float thr = fixthr[slot];
        float4 zv = *(const float4*)(z + (size_t)row * DIM + lane * 4);
        const int cbase = split * CPS + w * 256;
        for (int cc = 0; cc < 256; cc += 4) {
            const float* cp = cb + (size_t)(cbase + cc) * DIM + lane * 4;
            float4 c0 = *(const float4*)(cp);
            float4 c1 = *(const float4*)(cp + DIM);
            float4 c2 = *(const float4*)(cp + 2 * DIM);
            float4 c3 = *(const float4*)(cp + 3 * DIM);
            float d0 = zv.x*c0.x + zv.y*c0.y + zv.z*c0.z + zv.w*c0.w;
            float d1 = zv.x*c1.x + zv.y*c1.y + zv.z*c1.z + zv.w*c1.w;
            float d2 = zv.x*c2.x + zv.y*c2.y + zv.z*c2.z + zv.w*c2.w;
            float d3 = zv.x*c3.x + zv.y*c3.y + zv.z*c3.z + zv.w*c3.w;
            #pragma unroll
            for (int off = 1; off < 64; off <<= 1) {
                d0 += __shfl_xor(d0, off);
                d1 += __shfl_xor(d1, off);
                d2 += __shfl_xor(d2, off);
                d3 += __shfl_xor(d3, off);
            }
            if (lane == 0) {
                if (d0 * 8192.0f >= thr) {
                    int pp = atomicAdd(npairs, 1);
                    if (pp < MAXPAIRS) pairs[pp] = make_int2(slot, cbase + cc);
                }
                if (d1 * 8192.0f >= thr) {
                    int pp = atomicAdd(npairs, 1);
                    if (pp < MAXPAIRS) pairs[pp] = make_int2(slot, cbase + cc + 1);
                }
                if (d2 * 8192.0f >= thr) {
                    int pp = atomicAdd(npairs, 1);
                    if (pp < MAXPAIRS) pairs[pp] = make_int2(slot, cbase + cc + 2);
                }
                if (d3 * 8192.0f >= thr) {
                    int pp = atomicAdd(npairs, 1);
                    if (pp < MAXPAIRS) pairs[pp] = make_int2(slot, cbase + cc + 3);
                }
            }
        }
    }
}

// ------- K4: exact f64 dot per candidate, fp32-rounded ref value, packed atomicMin -------
__global__ __launch_bounds__(256) void k_exact(
    const float* __restrict__ z, const float* __restrict__ cb,
    const float* __restrict__ sum1, const int* __restrict__ npairs_p,
    const int2* __restrict__ pairs, const int* __restrict__ fixl,
    unsigned long long* __restrict__ slotkey)
{
    int np = *npairs_p; if (np > MAXPAIRS) np = MAXPAIRS;
    const int lane = threadIdx.x & 63;
    const int wid = blockIdx.x * 4 + (threadIdx.x >> 6);
    for (int p = wid; p < np; p += gridDim.x * 4) {
        const int slot = pairs[p].x, code = pairs[p].y;
        const int row = fixl[slot];
        float4 a = *(const float4*)(z  + (size_t)row  * DIM + lane * 4);
        float4 c = *(const float4*)(cb + (size_t)code * DIM + lane * 4);
        double d = (double)a.x * (double)c.x + (double)a.y * (double)c.y
                 + (double)a.z * (double)c.z + (double)a.w * (double)c.w;
        #pragma unroll
        for (int off = 1; off < 64; off <<= 1) d += __shfl_xor(d, off);
        if (lane == 0) {
            float v = sum1[row] - 2.0f * (float)d;   // ||c||^2 < half-ulp: rounds away
            unsigned long long key =
                ((unsigned long long)__float_as_uint(v) << 32) | (unsigned)code;
            atomicMin(&slotkey[slot], key);          // min value, then min index
        }
    }
}

// ------- K5: finalize flagged rows + their count contribution -------
__global__ void k_fin(const int* __restrict__ flagc, const int* __restrict__ fixl,
                      const unsigned long long* __restrict__ slotkey,
                      int* __restrict__ idx_i, float* __restrict__ out_idx,
                      int* __restrict__ count)
{
    int nf = *flagc; if (nf > MAXFIX) nf = MAXFIX;
    int slot = blockIdx.x * 256 + threadIdx.x;
    if (slot >= nf) return;
    int r = fixl[slot];
    unsigned long long key = slotkey[slot];
    int idx;
    if (key != ~0ull) {
        idx = (int)(key & 0xFFFFFFFFull) & (NCODES - 1);
        idx_i[r] = idx;
        out_idx[r] = (float)idx;
    } else {
        idx = idx_i[r] & (NCODES - 1);
    }
    atomicAdd(&count[idx], 1);
}

// ------- K6: prefix over bins; necs/out_nec; n (fused scalar epilogue) -------
__global__ __launch_bounds__(256) void k_prefix(const int* __restrict__ count,
                                                const float* __restrict__ in_ec,
                                                int* __restrict__ binstart,
                                                int* __restrict__ bincur,
                                                float* __restrict__ necs,
                                                float* __restrict__ out_nec,
                                                float* __restrict__ n_cell)
{
    __shared__ int ts[257];
    __shared__ float red[256];
    const int t = threadIdx.x;
    int local[32];
    int s = 0;
    float ecs = 0.0f;
    #pragma unroll
    for (int k = 0; k < 32; ++k) {
        int i = t * 32 + k;
        local[k] = count[i];
        s += local[k];
        float e = in_ec[i];
        ecs += e;
        float nec = fmaf(0.99f, e, 0.01f * (float)local[k]);
        necs[i] = nec;
        out_nec[i] = nec;
    }
    ts[t + 1] = s;
    if (t == 0) ts[0] = 0;
    red[t] = ecs;
    __syncthreads();
    for (int off = 1; off < 256; off <<= 1) {
        int v = (t >= off) ? ts[t + 1 - off] : 0;
        __syncthreads();
        ts[t + 1] += v;
        __syncthreads();
    }
    int base = ts[t];
    #pragma unroll
    for (int k = 0; k < 32; ++k) {
        int i = t * 32 + k;
        binstart[i] = base;
        bincur[i]   = base;
        base += local[k];
    }
    for (int off = 128; off > 0; off >>= 1) {
        __syncthreads();
        if (t < off) red[t] += red[t + off];
    }
    __syncthreads();
    if (t == 0) *n_cell = fmaf(0.99f, red[0], 0.01f * 32768.0f);
}

// ------- K6c: counting-sort placement of row ids into code segments -------
__global__ void k_place(const int* __restrict__ idx_i, int* __restrict__ bincur,
                        int* __restrict__ sorted)
{
    int row = blockIdx.x * 256 + threadIdx.x;
    int idx = idx_i[row] & (NCODES - 1);
    int pos = atomicAdd(&bincur[idx], 1);
    sorted[pos] = row;
}

// ------- K8: one code per wave — zq scatter (cb row in regs), loss, segment z-sum,
//         new_ema_weight + new_codebook; last block finalizes vq_loss -------
__global__ __launch_bounds__(256) void k_wg(
    const float* __restrict__ z, const float* __restrict__ cb,
    const int* __restrict__ binstart, const int* __restrict__ count,
    const int* __restrict__ sorted, const float* __restrict__ in_ew,
    const float* __restrict__ necs, const float* __restrict__ n_cell,
    float* __restrict__ lossp, int* __restrict__ done,
    float* __restrict__ out_zq, float* __restrict__ out_ncb,
    float* __restrict__ out_new, float* __restrict__ out_loss)
{
    __shared__ int islast;
    __shared__ float lred[128];
    const int w = threadIdx.x >> 6, lane = threadIdx.x & 63;
    const int code = blockIdx.x * 4 + w;
    const int s0 = binstart[code], cnt = count[code];
    const int d0 = lane * 4;
    float4 cv = *(const float4*)(cb + (size_t)code * DIM + d0);
    float4 ws = {0.f, 0.f, 0.f, 0.f};
    float ls = 0.0f;
    int k = 0;
    for (; k + 2 <= cnt; k += 2) {
        int ra = sorted[s0 + k], rb = sorted[s0 + k + 1];
        float4 va = *(const float4*)(z + (size_t)ra * DIM + d0);
        float4 vb = *(const float4*)(z + (size_t)rb * DIM + d0);
        *(float4*)(out_zq + (size_t)ra * DIM + d0) = cv;
        *(float4*)(out_zq + (size_t)rb * DIM + d0) = cv;
        ws.x += va.x + vb.x; ws.y += va.y + vb.y;
        ws.z += va.z + vb.z; ws.w += va.w + vb.w;
        float ax = va.x - cv.x, ay = va.y - cv.y, az = va.z - cv.z, aw = va.w - cv.w;
        float bx = vb.x - cv.x, by = vb.y - cv.y, bz = vb.z - cv.z, bw = vb.w - cv.w;
        ls += ax*ax + ay*ay + az*az + aw*aw + bx*bx + by*by + bz*bz + bw*bw;
    }
    if (k < cnt) {
        int ra = sorted[s0 + k];
        float4 va = *(const float4*)(z + (size_t)ra * DIM + d0);
        *(float4*)(out_zq + (size_t)ra * DIM + d0) = cv;
        ws.x += va.x; ws.y += va.y; ws.z += va.z; ws.w += va.w;
        float ax = va.x - cv.x, ay = va.y - cv.y, az = va.z - cv.z, aw = va.w - cv.w;
        ls += ax*ax + ay*ay + az*az + aw*aw;
    }
    #pragma unroll
    for (int off = 1; off < 64; off <<= 1) ls += __shfl_xor(ls, off);
    if (lane == 0) atomicAdd(&lossp[code & 127], ls);

    size_t o = (size_t)code * DIM + d0;
    float4 ew4 = *(const float4*)(in_ew + o);
    float n = *n_cell;
    float nec = necs[code];
    float cs = (nec + 1e-5f) / (n + (float)NCODES * 1e-5f) * n;
    float4 nw, nc;
    nw.x = fmaf(0.99f, ew4.x, 0.01f * ws.x); nc.x = nw.x / cs;
    nw.y = fmaf(0.99f, ew4.y, 0.01f * ws.y); nc.y = nw.y / cs;
    nw.z = fmaf(0.99f, ew4.z, 0.01f * ws.z); nc.z = nw.z / cs;
    nw.w = fmaf(0.99f, ew4.w, 0.01f * ws.w); nc.w = nw.w / cs;
    *(float4*)(out_new + o) = nw;
    *(float4*)(out_ncb + o) = nc;

    // last-block loss finalize (device-scope atomic reads: L2-coherent across XCDs)
    __syncthreads();
    if (threadIdx.x == 0) {
        __threadfence();
        islast = (atomicAdd(done, 1) == (int)gridDim.x - 1) ? 1 : 0;
    }
    __syncthreads();
    if (islast) {
        if (threadIdx.x < 128) lred[threadIdx.x] = atomicAdd(&lossp[threadIdx.x], 0.0f);
        __syncthreads();
        if (threadIdx.x == 0) {
            float s = 0.f;
            for (int i = 0; i < 128; ++i) s += lred[i];
            out_loss[0] = 0.25f * s / 8388608.0f;
        }
    }
}

extern "C" void kernel_launch(void* const* d_in, const int* in_sizes, int n_in,
                              void* d_out, int out_size, void* d_ws, size_t ws_size,
                              hipStream_t stream)
{
    const float* z  = nullptr;
    const float* cb = nullptr;
    const float* ec = nullptr;
    const float* ew = nullptr;
    for (int i = 0; i < n_in; ++i) {
        if (in_sizes[i] == NROWS * DIM)       z  = (const float*)d_in[i];
        else if (in_sizes[i] == NCODES)       ec = (const float*)d_in[i];
        else if (in_sizes[i] == NCODES * DIM) { if (!cb) cb = (const float*)d_in[i]; else ew = (const float*)d_in[i]; }
    }
    if (!z)  z  = (const float*)d_in[0];
    if (!cb) cb = (const float*)d_in[1];
    if (!ec) ec = (const float*)d_in[2];
    if (!ew) ew = cb;
    float* out = (float*)d_out;

    char* ws = (char*)d_ws;
    int*    count   = (int*)   (ws + 0);           //    32,768 B (zeroed)
    float*  lossp   = (float*) (ws + 32768);       //       512 B (zeroed)
    float*  n_cell  = (float*) (ws + 33280);       //         4 B (zeroed)
    int*    flagc   = (int*)   (ws + 33284);       //         4 B (zeroed)
    int*    npairs  = (int*)   (ws + 33288);       //         4 B (zeroed)
    unsigned* cmax2 = (unsigned*)(ws + 33292);     //         4 B (zeroed)
    int*    nresc   = (int*)   (ws + 33296);       //         4 B (zeroed)
    int*    done    = (int*)   (ws + 33300);       //         4 B (zeroed) + pad -> 33312
    float*  sum1    = (float*) (ws + 33312);       //   131,072 B
    float*  pm1     = (float*) (ws + 164384);      // 1,048,576 B
    float*  pm2     = (float*) (ws + 1212960);     // 1,048,576 B
    float*  pm3     = (float*) (ws + 2261536);     // 1,048,576 B
    int*    fixl    = (int*)   (ws + 3310112);     //    98,304 B
    float*  fixthr  = (float*) (ws + 3408416);     //    98,304 B
    unsigned long long* slotkey = (unsigned long long*)(ws + 3506720); // 196,608 B
    int2*   pairs   = (int2*)  (ws + 3703328);     // 2,097,152 B
    int2*   resc    = (int2*)  (ws + 5800480);     // 1,572,864 B
    int*    idx_i   = (int*)   (ws + 7373344);     //   131,072 B
    float*  necs    = (float*) (ws + 7504416);     //    32,768 B
    int*    binstart= (int*)   (ws + 7537184);     //    32,768 B
    int*    bincur  = (int*)   (ws + 7569952);     //    32,768 B
    int*    sorted  = (int*)   (ws + 7602720);     //   131,072 B
    unsigned short* bh_g = (unsigned short*)(ws + 7733792);  // 4,194,304 B  total ~11.9 MB

    float* out_zq   = out;                // z_q            8,388,608 (fp32)
    float* out_idx  = out + 8388608;      // indices           32,768
    float* out_loss = out + 8421376;      // vq_loss                1
    float* out_ncb  = out + 8421377;      // new_codebook   2,097,152
    float* out_nec  = out + 10518529;     // new_ema_count      8,192
    float* out_new  = out + 10526721;     // new_ema_weight 2,097,152

    hipMemsetAsync(d_ws, 0, 33312, stream);
    hipMemsetAsync(slotkey, 0xFF, (size_t)MAXFIX * 8, stream);
    k_prep   <<<2048,  256, 0, stream>>>(cb, z, bh_g, cmax2, sum1);
    k_dist   <<<1024,  256, 0, stream>>>(z, bh_g, pm1, pm2, pm3);
    k_combine<<<128,   256, 0, stream>>>(pm1, pm2, pm3, sum1, cmax2, idx_i, out_idx,
                                         flagc, fixl, fixthr, npairs, pairs, nresc, resc,
                                         count);
    k_resc   <<<512,   256, 0, stream>>>(z, cb, nresc, resc, fixl, fixthr, npairs, pairs);
    k_exact  <<<4096,  256, 0, stream>>>(z, cb, sum1, npairs, pairs, fixl, slotkey);
    k_fin    <<<96,    256, 0, stream>>>(flagc, fixl, slotkey, idx_i, out_idx, count);
    k_prefix <<<1,     256, 0, stream>>>(count, ec, binstart, bincur, necs, out_nec, n_cell);
    k_place  <<<128,   256, 0, stream>>>(idx_i, bincur, sorted);
    k_wg     <<<NCODES/4, 256, 0, stream>>>(z, cb, binstart, count, sorted, ew, necs,
                                            n_cell, lossp, done, out_zq, out_ncb,
                                            out_new, out_loss);
}

// Round 11
// 483.344 us; speedup vs baseline: 1.1692x; 1.1692x over previous
//
#include <hip/hip_runtime.h>
#include <stdint.h>

#define NROWS   32768
#define NCODES  8192
#define DIM     256
#define NSPLIT  8
#define CPS     1024
#define MAXFIX  24576
#define MAXPAIRS 262144
#define MAXRESC (MAXFIX * NSPLIT)

typedef __attribute__((ext_vector_type(8))) _Float16 f16x8;
typedef __attribute__((ext_vector_type(4))) float f32x4;

// convert 8 fp32 (16B-aligned) to fp16 RNE
__device__ __forceinline__ f16x8 cvt8h(const float* __restrict__ p) {
    float4 a = *(const float4*)p;
    float4 b = *(const float4*)(p + 4);
    f16x8 H;
    H[0] = (_Float16)a.x; H[1] = (_Float16)a.y;
    H[2] = (_Float16)a.z; H[3] = (_Float16)a.w;
    H[4] = (_Float16)b.x; H[5] = (_Float16)b.y;
    H[6] = (_Float16)b.z; H[7] = (_Float16)b.w;
    return H;
}

// ------- K_prep: [blocks 0..1023] cb -> fp16(c*8192) XOR-permuted + max||c||^2
//                 [blocks 1024..2047] bit-exact pairwise fp32 sum of z*z per row -------
__global__ __launch_bounds__(256) void k_prep(const float* __restrict__ cb,
                                              const float* __restrict__ z,
                                              unsigned short* __restrict__ bh,
                                              unsigned* __restrict__ cmax2,
                                              float* __restrict__ sum1) {
    __shared__ float zz[32 * 257];
    const int t = threadIdx.x;
    if (blockIdx.x < 1024) {
        int i = blockIdx.x * 256 + t;               // global 16B-unit index
        const float* p = cb + (size_t)i * 8;
        float4 a = *(const float4*)p;
        float4 b = *(const float4*)(p + 4);
        f16x8 H;
        H[0] = (_Float16)(a.x * 8192.0f); H[1] = (_Float16)(a.y * 8192.0f);
        H[2] = (_Float16)(a.z * 8192.0f); H[3] = (_Float16)(a.w * 8192.0f);
        H[4] = (_Float16)(b.x * 8192.0f); H[5] = (_Float16)(b.y * 8192.0f);
        H[6] = (_Float16)(b.z * 8192.0f); H[7] = (_Float16)(b.w * 8192.0f);
        int j = (i & ~31) | ((i & 31) ^ ((i >> 5) & 7));
        *(f16x8*)(bh + (size_t)j * 8) = H;
        float ss = a.x*a.x + a.y*a.y + a.z*a.z + a.w*a.w
                 + b.x*b.x + b.y*b.y + b.z*b.z + b.w*b.w;
        #pragma unroll
        for (int off = 1; off < 32; off <<= 1) ss += __shfl_xor(ss, off);
        if ((t & 31) == 0) atomicMax(cmax2, __float_as_uint(ss));
        return;
    }
    const int bid = blockIdx.x - 1024;
    const size_t base = (size_t)bid * 32 * 256;
    #pragma unroll
    for (int k = 0; k < 8; ++k) {
        int f4 = t + k * 256;                       // 0..2047
        float4 v = *(const float4*)(z + base + (size_t)f4 * 4);
        int row = f4 >> 6, col = (f4 & 63) * 4;
        float* d = &zz[row * 257 + col];
        d[0] = v.x * v.x; d[1] = v.y * v.y; d[2] = v.z * v.z; d[3] = v.w * v.w;
    }
    __syncthreads();
    if (t < 32) {
        const float* x = &zz[t * 257];
        float tot = 0.0f;
        #pragma unroll
        for (int h = 0; h < 2; ++h) {
            float r0 = x[0], r1 = x[1], r2 = x[2], r3 = x[3];
            float r4 = x[4], r5 = x[5], r6 = x[6], r7 = x[7];
            for (int i = 8; i < 128; i += 8) {
                r0 += x[i + 0]; r1 += x[i + 1]; r2 += x[i + 2]; r3 += x[i + 3];
                r4 += x[i + 4]; r5 += x[i + 5]; r6 += x[i + 6]; r7 += x[i + 7];
            }
            float bsum = ((r0 + r1) + (r2 + r3)) + ((r4 + r5) + (r6 + r7));
            tot = (h == 0) ? bsum : (tot + bsum);
            x += 128;
        }
        sum1[bid * 32 + t] = tot;
    }
}

// async-stage one 32-code fp16 tile (16 KiB) into linear LDS via global->LDS DMA.
__device__ __forceinline__ void stage_h(const unsigned short* __restrict__ gh,
                                        int cbase, int w, int lane,
                                        unsigned short* B) {
    const unsigned short* sh = gh + (size_t)cbase * 256;
    #pragma unroll
    for (int k = 0; k < 4; ++k) {
        const int ub = k * 256 + w * 64;            // 16B-unit base for this wave/call
        __builtin_amdgcn_global_load_lds(
            (const __attribute__((address_space(1))) void*)(sh + (size_t)(ub + lane) * 8),
            (__attribute__((address_space(3))) void*)(B + (size_t)ub * 8), 16, 0, 0);
    }
}

// ------- K1: fp16 MAX-dot GEMM, indexless med3 top-3 with index-in-mantissa keys -------
// VERIFIED round-8 config (183us): 32-code rounds, 2x16KB double buffer, one
// __syncthreads per round. r9 (counted vmcnt) and r10 (64-code tile) were both
// neutral-to-negative: this structure's floor is intra-wave dependency stall.
// (r7 lesson: launch_bounds(256,4) spills A-frags -> keep (256,2), 128 VGPR.)
__global__ __launch_bounds__(256, 2) void k_dist(
    const float* __restrict__ z,
    const unsigned short* __restrict__ bh,
    float* __restrict__ pm1, float* __restrict__ pm2, float* __restrict__ pm3)
{
    __shared__ __align__(16) unsigned short Bs[2][32][256];      // 32 KiB double-buffer

    const int bid   = blockIdx.x;                   // 128 row-tiles x 8 splits
    const int split = bid & (NSPLIT - 1);
    const int rt    = bid >> 3;
    const int rowbase = rt * 256;
    const int cbase0  = split * CPS;

    const int t    = threadIdx.x;
    const int w    = t >> 6;
    const int lane = t & 63;
    const int quad = lane >> 4;
    const int l15  = lane & 15;

    // prologue: kick round-0 DMA, convert A under its latency
    stage_h(bh, cbase0, w, lane, &Bs[0][0][0]);

    f16x8 Af[4][8];                                  // 64 rows x K=256 fp16
    const int rbase = rowbase + w * 64;
    #pragma unroll
    for (int mt = 0; mt < 4; ++mt) {
        const float* zp = z + (size_t)(rbase + mt*16 + l15) * DIM + quad * 8;
        #pragma unroll
        for (int ks = 0; ks < 8; ++ks)
            Af[mt][ks] = cvt8h(zp + ks * 32);
    }

    int offB[2][8];                                  // swizzled LDS byte offsets (buf0 base)
    #pragma unroll
    for (int nt = 0; nt < 2; ++nt) {
        const int cc = nt * 16 + l15;
        const int cx = cc & 7;
        #pragma unroll
        for (int ks = 0; ks < 8; ++ks)
            offB[nt][ks] = cc * 512 + (((quad + 4 * ks) ^ cx) * 16);
    }
    const unsigned idx0 = 8191u - (unsigned)(cbase0 + l15);      // nt=0 index bits @round 0

    float m1[16], m2[16], m3[16];
    #pragma unroll
    for (int s = 0; s < 16; ++s) { m1[s] = -3.4e38f; m2[s] = -3.4e38f; m3[s] = -3.4e38f; }

    __syncthreads();                                 // round-0 tile ready (vmcnt drained)

#define KD_ROUND(RND, BCUR, BNXT)                                               \
    {                                                                           \
        if ((RND) + 1 < CPS / 32)                                               \
            stage_h(bh, cbase0 + ((RND) + 1) * 32, w, lane, (BNXT));            \
        const char* baseB = (const char*)(BCUR);                                \
        _Pragma("unroll")                                                       \
        for (int nt = 0; nt < 2; ++nt) {                                        \
            f32x4 a0 = {0,0,0,0}, a1 = {0,0,0,0}, a2 = {0,0,0,0}, a3 = {0,0,0,0};\
            _Pragma("unroll")                                                   \
            for (int ks = 0; ks < 8; ++ks) {                                    \
                f16x8 Bk = *(const f16x8*)(baseB + offB[nt][ks]);               \
                a0 = __builtin_amdgcn_mfma_f32_16x16x32_f16(Af[0][ks], Bk, a0, 0, 0, 0); \
                a1 = __builtin_amdgcn_mfma_f32_16x16x32_f16(Af[1][ks], Bk, a1, 0, 0, 0); \
                a2 = __builtin_amdgcn_mfma_f32_16x16x32_f16(Af[2][ks], Bk, a2, 0, 0, 0); \
                a3 = __builtin_amdgcn_mfma_f32_16x16x32_f16(Af[3][ks], Bk, a3, 0, 0, 0); \
            }                                                                   \
            const unsigned ibnt = idx0 - (unsigned)((RND) * 32 + nt * 16);      \
            _Pragma("unroll")                                                   \
            for (int mt = 0; mt < 4; ++mt) {                                    \
                _Pragma("unroll")                                               \
                for (int r = 0; r < 4; ++r) {                                   \
                    float dot = mt == 0 ? a0[r] : mt == 1 ? a1[r] : mt == 2 ? a2[r] : a3[r]; \
                    unsigned kb = (__float_as_uint(dot) & 0xFFFFE000u) | ibnt;  \
                    float kf = __uint_as_float(kb);                             \
                    int s = mt * 4 + r;                                         \
                    m3[s] = __builtin_amdgcn_fmed3f(m2[s], m3[s], kf);          \
                    m2[s] = __builtin_amdgcn_fmed3f(m1[s], m2[s], kf);          \
                    m1[s] = fmaxf(m1[s], kf);                                   \
                }                                                               \
            }                                                                   \
        }                                                                       \
        __syncthreads();                                                        \
    }

    for (int r2 = 0; r2 < CPS / 64; ++r2) {
        KD_ROUND(2 * r2,     &Bs[0][0][0], &Bs[1][0][0]);
        KD_ROUND(2 * r2 + 1, &Bs[1][0][0], &Bs[0][0][0]);
    }
#undef KD_ROUND

    #pragma unroll
    for (int off = 1; off < 16; off <<= 1) {
        #pragma unroll
        for (int s = 0; s < 16; ++s) {
            float o1 = __shfl_xor(m1[s], off);
            float o2 = __shfl_xor(m2[s], off);
            float o3 = __shfl_xor(m3[s], off);
            m3[s] = __builtin_amdgcn_fmed3f(m2[s], m3[s], o1);
            m2[s] = __builtin_amdgcn_fmed3f(m1[s], m2[s], o1);
            m1[s] = fmaxf(m1[s], o1);
            m3[s] = __builtin_amdgcn_fmed3f(m2[s], m3[s], o2);
            m2[s] = __builtin_amdgcn_fmed3f(m1[s], m2[s], o2);
            m1[s] = fmaxf(m1[s], o2);
            m3[s] = __builtin_amdgcn_fmed3f(m2[s], m3[s], o3);
            m2[s] = __builtin_amdgcn_fmed3f(m1[s], m2[s], o3);
            m1[s] = fmaxf(m1[s], o3);
        }
    }
    if (l15 == 0) {
        #pragma unroll
        for (int s = 0; s < 16; ++s) {
            int mt = s >> 2, r = s & 3;
            int row = rbase + mt * 16 + quad * 4 + r;
            pm1[row * NSPLIT + split] = m1[s];
            pm2[row * NSPLIT + split] = m2[s];
            pm3[row * NSPLIT + split] = m3[s];
        }
    }
}

// ------- K2: merge splits; flag ambiguous rows; WAVE-AGGREGATED atomics -------
// ~23k same-address atomicAdds (flagc/npairs) serialized at the L2 slot; ballot
// compaction + shfl prefix-sum cut this to ~1 atomic per wave per list (G12).
// slotkey init (was a 196KB memset dispatch) is folded in per new slot.
__global__ void k_combine(const float* __restrict__ pm1, const float* __restrict__ pm2,
                          const float* __restrict__ pm3, const float* __restrict__ sum1,
                          const unsigned* __restrict__ cmax2,
                          int* __restrict__ idx_i, float* __restrict__ out_idx,
                          int* __restrict__ flagc, int* __restrict__ fixl,
                          float* __restrict__ fixthr, int* __restrict__ npairs,
                          int2* __restrict__ pairs, int* __restrict__ nresc,
                          int2* __restrict__ resc, int* __restrict__ count,
                          unsigned long long* __restrict__ slotkey)
{
    int r = blockIdx.x * 256 + threadIdx.x;
    const int lane = threadIdx.x & 63;
    float a[8], b[8], c[8];
    #pragma unroll
    for (int s = 0; s < NSPLIT; ++s) {
        a[s] = pm1[r * NSPLIT + s];
        b[s] = pm2[r * NSPLIT + s];
        c[s] = pm3[r * NSPLIT + s];
    }
    float M1 = -3.4e38f, M2 = -3.4e38f;
    #pragma unroll
    for (int s = 0; s < NSPLIT; ++s) {
        M2 = fmaxf(fmaxf(M2, b[s]), fminf(M1, a[s]));
        M1 = fmaxf(M1, a[s]);
    }
    int I1 = (int)(8191u - (__float_as_uint(M1) & 8191u));
    idx_i[r] = I1;
    out_idx[r] = (float)I1;
    float cn = sqrtf(__uint_as_float(*cmax2)) * 8192.0f;         // scaled max ||c||
    float ds = 9.80e-4f * sqrtf(sum1[r]) * cn + 3e-3f;           // scaled fp16-dot bound
    float t1 = sum1[r] - M1 * 0x1p-12f;                          // ref's fp32 dist value
    unsigned eb = (__float_as_uint(t1 + 0.05f) >> 23) & 0xFFu;   // biased exponent
    float q = __uint_as_float((eb - 23u) << 23);                 // ulp of t1's binade
    // window: fp32-grid slack + 2x dot error + 2x packing perturbation (2^-5) + cushion
    bool want = (M1 - M2 <= (q + 2e-6f) * 8192.0f + 2.0f * ds + 0.0655f);

    // --- wave-aggregated flagc allocation ---
    unsigned long long wm = __ballot(want);
    int base = 0;
    if (wm != 0ull) {
        if (lane == 0) base = atomicAdd(flagc, (int)__popcll(wm));
        base = __shfl(base, 0);
    }
    int p = base + (int)__popcll(wm & ((1ull << lane) - 1ull));
    bool fixed = want && (p < MAXFIX);

    float thr = 0.0f;
    int ecnt = 0;
    bool ea[8], ebb[8], ecc[8];
    #pragma unroll
    for (int s = 0; s < NSPLIT; ++s) { ea[s] = false; ebb[s] = false; ecc[s] = false; }
    if (fixed) {
        fixl[p] = r;
        thr = M1 - ((1.25f * q + 4e-6f) * 8192.0f + 2.2f * ds + 0.16f);
        fixthr[p] = thr;
        slotkey[p] = ~0ull;
        #pragma unroll
        for (int s = 0; s < NSPLIT; ++s) {
            ea[s]  = (a[s] >= thr);
            ebb[s] = (b[s] >= thr);
            ecc[s] = (c[s] >= thr);
            ecnt += (int)ea[s] + (int)ebb[s] + (int)ecc[s];
        }
    }
    // --- wave prefix-sum allocation into pairs ---
    int off = ecnt;
    #pragma unroll
    for (int d = 1; d < 64; d <<= 1) {
        int o = __shfl_up(off, d);
        if (lane >= d) off += o;
    }
    int tot = __shfl(off, 63);
    int pb = 0;
    if (tot > 0) {
        if (lane == 63) pb = atomicAdd(npairs, tot);
        pb = __shfl(pb, 63);
    }
    int wpos = pb + off - ecnt;
    if (fixed) {
        #pragma unroll
        for (int s = 0; s < NSPLIT; ++s) {
            if (ea[s]) {
                if (wpos < MAXPAIRS)
                    pairs[wpos] = make_int2(p, (int)(8191u - (__float_as_uint(a[s]) & 8191u)));
                ++wpos;
            }
            if (ebb[s]) {
                if (wpos < MAXPAIRS)
                    pairs[wpos] = make_int2(p, (int)(8191u - (__float_as_uint(b[s]) & 8191u)));
                ++wpos;
            }
            if (ecc[s]) {                            // codes ranked >=3 unbounded: rescan split
                if (wpos < MAXPAIRS)
                    pairs[wpos] = make_int2(p, (int)(8191u - (__float_as_uint(c[s]) & 8191u)));
                ++wpos;
                int q2 = atomicAdd(nresc, 1);        // rare (~0 events expected)
                if (q2 < MAXRESC) resc[q2] = make_int2(p, s);
            }
        }
    }
    if (!fixed) atomicAdd(&count[I1], 1);            // flagged rows counted in k_fin
}

// ------- K3: rare split rescans — fp32 dots, 4 codes in flight (latency-pipelined) -------
__global__ __launch_bounds__(256) void k_resc(
    const float* __restrict__ z, const float* __restrict__ cb,
    const int* __restrict__ nresc_p, const int2* __restrict__ resc,
    const int* __restrict__ fixl, const float* __restrict__ fixthr,
    int* __restrict__ npairs, int2* __restrict__ pairs)
{
    int nr = *nresc_p; if (nr > MAXRESC) nr = MAXRESC;
    const int w = threadIdx.x >> 6, lane = threadIdx.x & 63;
    for (int it = blockIdx.x; it < nr; it += gridDim.x) {
        const int slot = resc[it].x, split = resc[it].y;
        const int row = fixl[slot];
        const float thr = fixthr[slot];
        float4 zv = *(const float4*)(z + (size_t)row * DIM + lane * 4);
        const int cbase = split * CPS + w * 256;
        for (int cc = 0; cc < 256; cc += 4) {
            const float* cp = cb + (size_t)(cbase + cc) * DIM + lane * 4;
            float4 c0 = *(const float4*)(cp);
            float4 c1 = *(const float4*)(cp + DIM);
            float4 c2 = *(const float4*)(cp + 2 * DIM);
            float4 c3 = *(const float4*)(cp + 3 * DIM);
            float d0 = zv.x*c0.x + zv.y*c0.y + zv.z*c0.z + zv.w*c0.w;
            float d1 = zv.x*c1.x + zv.y*c1.y + zv.z*c1.z + zv.w*c1.w;
            float d2 = zv.x*c2.x + zv.y*c2.y + zv.z*c2.z + zv.w*c2.w;
            float d3 = zv.x*c3.x + zv.y*c3.y + zv.z*c3.z + zv.w*c3.w;
            #pragma unroll
            for (int off = 1; off < 64; off <<= 1) {
                d0 += __shfl_xor(d0, off);
                d1 += __shfl_xor(d1, off);
                d2 += __shfl_xor(d2, off);
                d3 += __shfl_xor(d3, off);
            }
            if (lane == 0) {
                if (d0 * 8192.0f >= thr) {
                    int pp = atomicAdd(npairs, 1);
                    if (pp < MAXPAIRS) pairs[pp] = make_int2(slot, cbase + cc);
                }
                if (d1 * 8192.0f >= thr) {
                    int pp = atomicAdd(npairs, 1);
                    if (pp < MAXPAIRS) pairs[pp] = make_int2(slot, cbase + cc + 1);
                }
                if (d2 * 8192.0f >= thr) {
                    int pp = atomicAdd(npairs, 1);
                    if (pp < MAXPAIRS) pairs[pp] = make_int2(slot, cbase + cc + 2);
                }
                if (d3 * 8192.0f >= thr) {
                    int pp = atomicAdd(npairs, 1);
                    if (pp < MAXPAIRS) pairs[pp] = make_int2(slot, cbase + cc + 3);
                }
            }
        }
    }
}

// ------- K4: exact f64 dot per candidate, fp32-rounded ref value, packed atomicMin -------
__global__ __launch_bounds__(256) void k_exact(
    const float* __restrict__ z, const float* __restrict__ cb,
    const float* __restrict__ sum1, const int* __restrict__ npairs_p,
    const int2* __restrict__ pairs, const int* __restrict__ fixl,
    unsigned long long* __restrict__ slotkey)
{
    int np = *npairs_p; if (np > MAXPAIRS) np = MAXPAIRS;
    const int lane = threadIdx.x & 63;
    const int wid = blockIdx.x * 4 + (threadIdx.x >> 6);
    for (int p = wid; p < np; p += gridDim.x * 4) {
        const int slot = pairs[p].x, code = pairs[p].y;
        const int row = fixl[slot];
        float4 a = *(const float4*)(z  + (size_t)row  * DIM + lane * 4);
        float4 c = *(const float4*)(cb + (size_t)code * DIM + lane * 4);
        double d = (double)a.x * (double)c.x + (double)a.y * (double)c.y
                 + (double)a.z * (double)c.z + (double)a.w * (double)c.w;
        #pragma unroll
        for (int off = 1; off < 64; off <<= 1) d += __shfl_xor(d, off);
        if (lane == 0) {
            float v = sum1[row] - 2.0f * (float)d;   // ||c||^2 < half-ulp: rounds away
            unsigned long long key =
                ((unsigned long long)__float_as_uint(v) << 32) | (unsigned)code;
            atomicMin(&slotkey[slot], key);          // min value, then min index
        }
    }
}

// ------- K5: finalize flagged rows + their count contribution -------
__global__ void k_fin(const int* __restrict__ flagc, const int* __restrict__ fixl,
                      const unsigned long long* __restrict__ slotkey,
                      int* __restrict__ idx_i, float* __restrict__ out_idx,
                      int* __restrict__ count)
{
    int nf = *flagc; if (nf > MAXFIX) nf = MAXFIX;
    int slot = blockIdx.x * 256 + threadIdx.x;
    if (slot >= nf) return;
    int r = fixl[slot];
    unsigned long long key = slotkey[slot];
    int idx;
    if (key != ~0ull) {
        idx = (int)(key & 0xFFFFFFFFull) & (NCODES - 1);
        idx_i[r] = idx;
        out_idx[r] = (float)idx;
    } else {
        idx = idx_i[r] & (NCODES - 1);
    }
    atomicAdd(&count[idx], 1);
}

// ------- K6: prefix over bins; necs/out_nec; n (fused scalar epilogue) -------
__global__ __launch_bounds__(256) void k_prefix(const int* __restrict__ count,
                                                const float* __restrict__ in_ec,
                                                int* __restrict__ binstart,
                                                int* __restrict__ bincur,
                                                float* __restrict__ necs,
                                                float* __restrict__ out_nec,
                                                float* __restrict__ n_cell)
{
    __shared__ int ts[257];
    __shared__ float red[256];
    const int t = threadIdx.x;
    int local[32];
    int s = 0;
    float ecs = 0.0f;
    #pragma unroll
    for (int k = 0; k < 32; ++k) {
        int i = t * 32 + k;
        local[k] = count[i];
        s += local[k];
        float e = in_ec[i];
        ecs += e;
        float nec = fmaf(0.99f, e, 0.01f * (float)local[k]);
        necs[i] = nec;
        out_nec[i] = nec;
    }
    ts[t + 1] = s;
    if (t == 0) ts[0] = 0;
    red[t] = ecs;
    __syncthreads();
    for (int off = 1; off < 256; off <<= 1) {
        int v = (t >= off) ? ts[t + 1 - off] : 0;
        __syncthreads();
        ts[t + 1] += v;
        __syncthreads();
    }
    int base = ts[t];
    #pragma unroll
    for (int k = 0; k < 32; ++k) {
        int i = t * 32 + k;
        binstart[i] = base;
        bincur[i]   = base;
        base += local[k];
    }
    for (int off = 128; off > 0; off >>= 1) {
        __syncthreads();
        if (t < off) red[t] += red[t + off];
    }
    __syncthreads();
    if (t == 0) *n_cell = fmaf(0.99f, red[0], 0.01f * 32768.0f);
}

// ------- K6c: counting-sort placement of row ids into code segments -------
__global__ void k_place(const int* __restrict__ idx_i, int* __restrict__ bincur,
                        int* __restrict__ sorted)
{
    int row = blockIdx.x * 256 + threadIdx.x;
    int idx = idx_i[row] & (NCODES - 1);
    int pos = atomicAdd(&bincur[idx], 1);
    sorted[pos] = row;
}

// ------- K8: one code per wave — zq scatter (cb row in regs), loss, segment z-sum,
//         new_ema_weight + new_codebook; last block finalizes vq_loss -------
__global__ __launch_bounds__(256) void k_wg(
    const float* __restrict__ z, const float* __restrict__ cb,
    const int* __restrict__ binstart, const int* __restrict__ count,
    const int* __restrict__ sorted, const float* __restrict__ in_ew,
    const float* __restrict__ necs, const float* __restrict__ n_cell,
    float* __restrict__ lossp, int* __restrict__ done,
    float* __restrict__ out_zq, float* __restrict__ out_ncb,
    float* __restrict__ out_new, float* __restrict__ out_loss)
{
    __shared__ int islast;
    __shared__ float lred[128];
    const int w = threadIdx.x >> 6, lane = threadIdx.x & 63;
    const int code = blockIdx.x * 4 + w;
    const int s0 = binstart[code], cnt = count[code];
    const int d0 = lane * 4;
    float4 cv = *(const float4*)(cb + (size_t)code * DIM + d0);
    float4 ws = {0.f, 0.f, 0.f, 0.f};
    float ls = 0.0f;
    int k = 0;
    for (; k + 2 <= cnt; k += 2) {
        int ra = sorted[s0 + k], rb = sorted[s0 + k + 1];
        float4 va = *(const float4*)(z + (size_t)ra * DIM + d0);
        float4 vb = *(const float4*)(z + (size_t)rb * DIM + d0);
        *(float4*)(out_zq + (size_t)ra * DIM + d0) = cv;
        *(float4*)(out_zq + (size_t)rb * DIM + d0) = cv;
        ws.x += va.x + vb.x; ws.y += va.y + vb.y;
        ws.z += va.z + vb.z; ws.w += va.w + vb.w;
        float ax = va.x - cv.x, ay = va.y - cv.y, az = va.z - cv.z, aw = va.w - cv.w;
        float bx = vb.x - cv.x, by = vb.y - cv.y, bz = vb.z - cv.z, bw = vb.w - cv.w;
        ls += ax*ax + ay*ay + az*az + aw*aw + bx*bx + by*by + bz*bz + bw*bw;
    }
    if (k < cnt) {
        int ra = sorted[s0 + k];
        float4 va = *(const float4*)(z + (size_t)ra * DIM + d0);
        *(float4*)(out_zq + (size_t)ra * DIM + d0) = cv;
        ws.x += va.x; ws.y += va.y; ws.z += va.z; ws.w += va.w;
        float ax = va.x - cv.x, ay = va.y - cv.y, az = va.z - cv.z, aw = va.w - cv.w;
        ls += ax*ax + ay*ay + az*az + aw*aw;
    }
    #pragma unroll
    for (int off = 1; off < 64; off <<= 1) ls += __shfl_xor(ls, off);
    if (lane == 0) atomicAdd(&lossp[code & 127], ls);

    size_t o = (size_t)code * DIM + d0;
    float4 ew4 = *(const float4*)(in_ew + o);
    float n = *n_cell;
    float nec = necs[code];
    float cs = (nec + 1e-5f) / (n + (float)NCODES * 1e-5f) * n;
    float4 nw, nc;
    nw.x = fmaf(0.99f, ew4.x, 0.01f * ws.x); nc.x = nw.x / cs;
    nw.y = fmaf(0.99f, ew4.y, 0.01f * ws.y); nc.y = nw.y / cs;
    nw.z = fmaf(0.99f, ew4.z, 0.01f * ws.z); nc.z = nw.z / cs;
    nw.w = fmaf(0.99f, ew4.w, 0.01f * ws.w); nc.w = nw.w / cs;
    *(float4*)(out_new + o) = nw;
    *(float4*)(out_ncb + o) = nc;

    // last-block loss finalize (device-scope atomic reads: L2-coherent across XCDs)
    __syncthreads();
    if (threadIdx.x == 0) {
        __threadfence();
        islast = (atomicAdd(done, 1) == (int)gridDim.x - 1) ? 1 : 0;
    }
    __syncthreads();
    if (islast) {
        if (threadIdx.x < 128) lred[threadIdx.x] = atomicAdd(&lossp[threadIdx.x], 0.0f);
        __syncthreads();
        if (threadIdx.x == 0) {
            float s = 0.f;
            for (int i = 0; i < 128; ++i) s += lred[i];
            out_loss[0] = 0.25f * s / 8388608.0f;
        }
    }
}

extern "C" void kernel_launch(void* const* d_in, const int* in_sizes, int n_in,
                              void* d_out, int out_size, void* d_ws, size_t ws_size,
                              hipStream_t stream)
{
    const float* z  = nullptr;
    const float* cb = nullptr;
    const float* ec = nullptr;
    const float* ew = nullptr;
    for (int i = 0; i < n_in; ++i) {
        if (in_sizes[i] == NROWS * DIM)       z  = (const float*)d_in[i];
        else if (in_sizes[i] == NCODES)       ec = (const float*)d_in[i];
        else if (in_sizes[i] == NCODES * DIM) { if (!cb) cb = (const float*)d_in[i]; else ew = (const float*)d_in[i]; }
    }
    if (!z)  z  = (const float*)d_in[0];
    if (!cb) cb = (const float*)d_in[1];
    if (!ec) ec = (const float*)d_in[2];
    if (!ew) ew = cb;
    float* out = (float*)d_out;

    char* ws = (char*)d_ws;
    int*    count   = (int*)   (ws + 0);           //    32,768 B (zeroed)
    float*  lossp   = (float*) (ws + 32768);       //       512 B (zeroed)
    float*  n_cell  = (float*) (ws + 33280);       //         4 B (zeroed)
    int*    flagc   = (int*)   (ws + 33284);       //         4 B (zeroed)
    int*    npairs  = (int*)   (ws + 33288);       //         4 B (zeroed)
    unsigned* cmax2 = (unsigned*)(ws + 33292);     //         4 B (zeroed)
    int*    nresc   = (int*)   (ws + 33296);       //         4 B (zeroed)
    int*    done    = (int*)   (ws + 33300);       //         4 B (zeroed) + pad -> 33312
    float*  sum1    = (float*) (ws + 33312);       //   131,072 B
    float*  pm1     = (float*) (ws + 164384);      // 1,048,576 B
    float*  pm2     = (float*) (ws + 1212960);     // 1,048,576 B
    float*  pm3     = (float*) (ws + 2261536);     // 1,048,576 B
    int*    fixl    = (int*)   (ws + 3310112);     //    98,304 B
    float*  fixthr  = (float*) (ws + 3408416);     //    98,304 B
    unsigned long long* slotkey = (unsigned long long*)(ws + 3506720); // 196,608 B
    int2*   pairs   = (int2*)  (ws + 3703328);     // 2,097,152 B
    int2*   resc    = (int2*)  (ws + 5800480);     // 1,572,864 B
    int*    idx_i   = (int*)   (ws + 7373344);     //   131,072 B
    float*  necs    = (float*) (ws + 7504416);     //    32,768 B
    int*    binstart= (int*)   (ws + 7537184);     //    32,768 B
    int*    bincur  = (int*)   (ws + 7569952);     //    32,768 B
    int*    sorted  = (int*)   (ws + 7602720);     //   131,072 B
    unsigned short* bh_g = (unsigned short*)(ws + 7733792);  // 4,194,304 B  total ~11.9 MB

    float* out_zq   = out;                // z_q            8,388,608 (fp32)
    float* out_idx  = out + 8388608;      // indices           32,768
    float* out_loss = out + 8421376;      // vq_loss                1
    float* out_ncb  = out + 8421377;      // new_codebook   2,097,152
    float* out_nec  = out + 10518529;     // new_ema_count      8,192
    float* out_new  = out + 10526721;     // new_ema_weight 2,097,152

    hipMemsetAsync(d_ws, 0, 33312, stream);
    k_prep   <<<2048,  256, 0, stream>>>(cb, z, bh_g, cmax2, sum1);
    k_dist   <<<1024,  256, 0, stream>>>(z, bh_g, pm1, pm2, pm3);
    k_combine<<<128,   256, 0, stream>>>(pm1, pm2, pm3, sum1, cmax2, idx_i, out_idx,
                                         flagc, fixl, fixthr, npairs, pairs, nresc, resc,
                                         count, slotkey);
    k_resc   <<<512,   256, 0, stream>>>(z, cb, nresc, resc, fixl, fixthr, npairs, pairs);
    k_exact  <<<2048,  256, 0, stream>>>(z, cb, sum1, npairs, pairs, fixl, slotkey);
    k_fin    <<<96,    256, 0, stream>>>(flagc, fixl, slotkey, idx_i, out_idx, count);
    k_prefix <<<1,     256, 0, stream>>>(count, ec, binstart, bincur, necs, out_nec, n_cell);
    k_place  <<<128,   256, 0, stream>>>(idx_i, bincur, sorted);
    k_wg     <<<NCODES/4, 256, 0, stream>>>(z, cb, binstart, count, sorted, ew, necs,
                                            n_cell, lossp, done, out_zq, out_ncb,
                                            out_new, out_loss);
}